// Round 6
// baseline (516.525 us; speedup 1.0000x reference)
//
#include <hip/hip_runtime.h>
#include <math.h>

// LaughlinAnsatz: B=4096, N=32, D=3, Dp=4, H=64(!), F=32, Ho=64
// out[b] = odd_net(zs[b]) - odd_net(-zs[b])
// zs[b,f] = prod_{i<j} ( pair_net(xi,xj,xij)[f] - pair_net(xj,xi,xij)[f] )
//
//  pre_ij[k] = A_i[k] + B_j[k] + C_ij[k] + b1p[k],  k<64
//     A_i[k] = xs[i,:]@W1p[0:3,k], B_i[k] = xs[i,:]@W1p[3:6,k],
//     C_ij[k] = xij@W1p[6:10,k]        (W1p row-major (10,64)!)
//  factor_ij[f] = sum_{k<64} (tanh(pre_ij[k])-tanh(pre_ji[k])) * W2p[k,f]
//     (W2p row-major (64,32); b2p cancels)
//  zs[f] = prod over 496 pairs (fp64 running product: range ~e^-700 like np64)
//  out = [tanh(zs@W1o+b1o) - tanh(-zs@W1o+b1o)]@W2o  in fp64 (b2o cancels;
//     with b1o=0 this is exactly 2*hacc at tiny hacc -> no cancellation)
//
// Mapping: 1 wave (64 lanes) per batch row; lane k = hidden unit k for the
// pair phase; lane (f + 32*half) = feature f, k-half for the reduce phase.

#define NB 4096
#define NN 32
#define NPAIR 496

__global__ void laughlin_kernel(
    const float* __restrict__ xs,       // (B,32,3)
    const float* __restrict__ xs_pair,  // (B,32,32,4)
    const float* __restrict__ W1p,      // (10,64)
    const float* __restrict__ b1p,      // (64,)
    const float* __restrict__ W2p,      // (64,32)
    const float* __restrict__ W1o,      // (32,64)
    const float* __restrict__ b1o,      // (64,)
    const float* __restrict__ W2o,      // (64,1)
    float* __restrict__ out)            // (B,1)
{
    __shared__ float  ldsX[NN * 3];     // this row's xs (96 floats)
    __shared__ float  ldsD[2][64];      // d[k], double-buffered
    __shared__ double ldsZ[32];         // zs[f] (fp64)

    const int lane = threadIdx.x;       // 0..63, one wave per block
    const int hf   = lane >> 5;         // k-half for the reduce phase
    const int fq   = lane & 31;         // feature f for the reduce phase
    const int b    = blockIdx.x;        // batch row

    // ---- per-lane weights (lane = hidden unit k) ----
    const float wa0 = W1p[0 * 64 + lane], wa1 = W1p[1 * 64 + lane], wa2 = W1p[2 * 64 + lane];
    const float wb0 = W1p[3 * 64 + lane], wb1 = W1p[4 * 64 + lane], wb2 = W1p[5 * 64 + lane];
    const float wc0 = W1p[6 * 64 + lane], wc1 = W1p[7 * 64 + lane], wc2 = W1p[8 * 64 + lane];
    const float wc3 = W1p[9 * 64 + lane];
    const float b1  = b1p[lane];
    float w2c[32];                      // W2p[hf*32+kk, fq]
    #pragma unroll
    for (int kk = 0; kk < 32; ++kk) w2c[kk] = W2p[(hf * 32 + kk) * 32 + fq];

    // ---- stage this row's xs into LDS (96 floats) ----
    const float* xb = xs + (size_t)b * (NN * 3);
    for (int idx = lane; idx < NN * 3; idx += 64) ldsX[idx] = xb[idx];
    __syncthreads();

    // ---- main loop: 496 pairs, 1 per iteration, all 64 lanes = hidden units ----
    const float* xpb = xs_pair + (size_t)b * (NN * NN * 4);
    double pp = 1.0;                    // running product for feature fq (both halves identical)
    int i = 0, j = 1;
    for (int t = 0; t < NPAIR; ++t) {
        const float xi0 = ldsX[i * 3 + 0], xi1 = ldsX[i * 3 + 1], xi2 = ldsX[i * 3 + 2];
        const float xj0 = ldsX[j * 3 + 0], xj1 = ldsX[j * 3 + 1], xj2 = ldsX[j * 3 + 2];
        const float aI = xi0 * wa0 + xi1 * wa1 + xi2 * wa2;   // A_i[k]
        const float bI = xi0 * wb0 + xi1 * wb1 + xi2 * wb2;   // B_i[k]
        const float aJ = xj0 * wa0 + xj1 * wa1 + xj2 * wa2;   // A_j[k]
        const float bJ = xj0 * wb0 + xj1 * wb1 + xj2 * wb2;   // B_j[k]

        const float4 xij = *(const float4*)(xpb + ((i << 5) + j) * 4);
        const float c = xij.x * wc0 + xij.y * wc1 + xij.z * wc2 + xij.w * wc3 + b1;

        const float d = tanhf(aI + bJ + c) - tanhf(aJ + bI + c);

        const int buf = t & 1;
        ldsD[buf][lane] = d;
        __syncthreads();                // 1-wave block: cheap; makes d visible

        // factor[fq] = sum_{k<64} d[k] * W2p[k,fq]; this lane does its k-half
        float acc = 0.f;
        const float* dh = &ldsD[buf][hf << 5];
        #pragma unroll
        for (int kk = 0; kk < 32; ++kk) acc = fmaf(dh[kk], w2c[kk], acc);
        acc += __shfl_xor(acc, 32);     // full 64-sum; identical in both halves

        pp *= (double)acc;              // fp64 running product (range like np64)
        // NOTE: read of ldsD[buf] is protected from the write 2 iters later
        // by the next iteration's __syncthreads.

        if (++j == NN) { ++i; j = i + 1; }
    }

    // ---- zs -> LDS (fp64), then odd_net entirely in fp64 ----
    if (lane < 32) ldsZ[lane] = pp;
    __syncthreads();

    double hacc = 0.0;                  // lane = hidden unit h of odd_net (64)
    #pragma unroll
    for (int f = 0; f < 32; ++f) hacc += ldsZ[f] * (double)W1o[f * 64 + lane];
    const double bo = (double)b1o[lane];
    const double u  = tanh(hacc + bo) - tanh(bo - hacc);  // b2o cancels
    double y = u * (double)W2o[lane];
    #pragma unroll
    for (int off = 32; off; off >>= 1) y += __shfl_xor(y, off);
    if (lane == 0) out[b] = (float)y;
}

extern "C" void kernel_launch(void* const* d_in, const int* in_sizes, int n_in,
                              void* d_out, int out_size, void* d_ws, size_t ws_size,
                              hipStream_t stream) {
    const float* xs      = (const float*)d_in[0];
    const float* xs_pair = (const float*)d_in[1];
    const float* W1p     = (const float*)d_in[2];
    const float* b1p     = (const float*)d_in[3];
    const float* W2p     = (const float*)d_in[4];
    // d_in[5] = b2p (cancels in the antisymmetric difference)
    const float* W1o     = (const float*)d_in[6];
    const float* b1o     = (const float*)d_in[7];
    const float* W2o     = (const float*)d_in[8];
    // d_in[9] = b2o (cancels in odd_net(z) - odd_net(-z))
    float* out = (float*)d_out;

    hipLaunchKernelGGL(laughlin_kernel, dim3(NB), dim3(64), 0, stream,
                       xs, xs_pair, W1p, b1p, W2p, W1o, b1o, W2o, out);
}

// Round 7
// 382.831 us; speedup vs baseline: 1.3492x; 1.3492x over previous
//
#include <hip/hip_runtime.h>
#include <math.h>

// LaughlinAnsatz: B=4096, N=32, D=3, Dp=4, H=64, F=32, Ho=64
// out[b] = odd_net(zs[b]) - odd_net(-zs[b])
// zs[b,f] = prod_{i<j} ( pair_net(xi,xj,xij)[f] - pair_net(xj,xi,xij)[f] )
//
//  pre_ij[k] = A_i[k] + B_j[k] + C_ij[k] + b1p[k]  (k<64; W1p row-major (10,64))
//  factor_ij[f] = sum_k (tanh(pre_ij[k]) - tanh(pre_ji[k])) * W2p[k,f]  (b2p cancels)
//  zs[f] = fp64 running product over 496 pairs
//  out = [tanh(zs@W1o+b1o) - tanh(-zs@W1o+b1o)]@W2o in fp64 (b2o cancels)
//
// R7: VALU-issue reduction. fast_tanh (v_exp+v_rcp, 5 ops vs ~25 for libm),
// zero barriers (wave-local LDS, in-order DS), 4 waves/block for occupancy,
// A_i/B_i hoisted out of the inner loop, xs staged as float4 in LDS.

#define NB 4096
#define NN 32

#if defined(__has_builtin) && __has_builtin(__builtin_amdgcn_exp2f) && __has_builtin(__builtin_amdgcn_rcpf)
__device__ __forceinline__ float fast_tanh(float x) {
    // tanh(x) = 1 - 2/(exp2(2*log2e*x)+1); saturates correctly at +-inf.
    float e = __builtin_amdgcn_exp2f(x * 2.8853900817779268f);
    float r = __builtin_amdgcn_rcpf(e + 1.0f);
    return fmaf(-2.0f, r, 1.0f);
}
#else
__device__ __forceinline__ float fast_tanh(float x) {
    float e = __expf(2.0f * x);
    return fmaf(-2.0f, 1.0f / (e + 1.0f), 1.0f);
}
#endif

__global__ void laughlin_kernel(
    const float* __restrict__ xs,       // (B,32,3)
    const float* __restrict__ xs_pair,  // (B,32,32,4)
    const float* __restrict__ W1p,      // (10,64)
    const float* __restrict__ b1p,      // (64,)
    const float* __restrict__ W2p,      // (64,32)
    const float* __restrict__ W1o,      // (32,64)
    const float* __restrict__ b1o,      // (64,)
    const float* __restrict__ W2o,      // (64,1)
    float* __restrict__ out)            // (B,1)
{
    // all LDS is wave-private: no __syncthreads anywhere
    __shared__ __align__(16) float  ldsX4[4][NN][4];  // xs row, float4-padded
    __shared__ __align__(16) float  ldsD[4][64];      // d[k] for current pair
    __shared__ __align__(16) double ldsZ[4][32];      // zs[f] (fp64)

    const int wv   = threadIdx.x >> 6;  // wave in block = row slot
    const int lane = threadIdx.x & 63;  // lane = hidden unit k in pair phase
    const int hf   = lane >> 5;         // k-half in reduce phase
    const int fq   = lane & 31;         // feature f in reduce phase
    const int b    = blockIdx.x * 4 + wv;

    // ---- per-lane weights (lane = hidden unit k) ----
    const float wa0 = W1p[0 * 64 + lane], wa1 = W1p[1 * 64 + lane], wa2 = W1p[2 * 64 + lane];
    const float wb0 = W1p[3 * 64 + lane], wb1 = W1p[4 * 64 + lane], wb2 = W1p[5 * 64 + lane];
    const float wc0 = W1p[6 * 64 + lane], wc1 = W1p[7 * 64 + lane], wc2 = W1p[8 * 64 + lane];
    const float wc3 = W1p[9 * 64 + lane];
    const float b1  = b1p[lane];
    float w2c[32];                      // W2p[hf*32+kk, fq]
    #pragma unroll
    for (int kk = 0; kk < 32; ++kk) w2c[kk] = W2p[(hf * 32 + kk) * 32 + fq];

    // ---- stage this row's xs into LDS as float4 (wave-local, no barrier) ----
    const float* xb = xs + (size_t)b * (NN * 3);
    if (lane < NN) {
        const float* p = xb + lane * 3;
        float4 v; v.x = p[0]; v.y = p[1]; v.z = p[2]; v.w = 0.f;
        *(float4*)&ldsX4[wv][lane][0] = v;
    }
    __builtin_amdgcn_wave_barrier();    // compiler fence (0-cost); DS is in-order per wave

    // ---- main loop: 496 pairs ----
    const float4* xp4 = (const float4*)(xs_pair + (size_t)b * (NN * NN * 4));
    double pp = 1.0;                    // running product for feature fq
    for (int i = 0; i < NN - 1; ++i) {
        const float4 xi = *(const float4*)&ldsX4[wv][i][0];
        const float aI = fmaf(xi.z, wa2, fmaf(xi.y, wa1, xi.x * wa0));
        const float bI = fmaf(xi.z, wb2, fmaf(xi.y, wb1, xi.x * wb0));
        for (int j = i + 1; j < NN; ++j) {
            const float4 xj = *(const float4*)&ldsX4[wv][j][0];
            const float aJ = fmaf(xj.z, wa2, fmaf(xj.y, wa1, xj.x * wa0));
            const float bJ = fmaf(xj.z, wb2, fmaf(xj.y, wb1, xj.x * wb0));

            const float4 xij = xp4[(i << 5) + j];
            const float c = fmaf(xij.w, wc3, fmaf(xij.z, wc2,
                            fmaf(xij.y, wc1, fmaf(xij.x, wc0, b1))));

            const float d = fast_tanh(aI + bJ + c) - fast_tanh(aJ + bI + c);

            ldsD[wv][lane] = d;
            __builtin_amdgcn_wave_barrier();  // keep write before reads (HW is in-order)

            // factor[fq] = sum_{k<64} d[k]*W2p[k,fq]; this lane does half, shfl sums
            float acc = 0.f;
            const float4* dh = (const float4*)&ldsD[wv][hf << 5];
            #pragma unroll
            for (int kk = 0; kk < 8; ++kk) {
                const float4 dv = dh[kk];
                acc = fmaf(dv.x, w2c[kk * 4 + 0], acc);
                acc = fmaf(dv.y, w2c[kk * 4 + 1], acc);
                acc = fmaf(dv.z, w2c[kk * 4 + 2], acc);
                acc = fmaf(dv.w, w2c[kk * 4 + 3], acc);
            }
            acc += __shfl_xor(acc, 32);       // full 64-sum (identical in both halves)

            pp *= (double)acc;                // fp64: range safety over 496 factors
            __builtin_amdgcn_wave_barrier();  // reads stay before next iter's write
        }
    }

    // ---- zs -> LDS (fp64), wave-local ----
    if (lane < 32) ldsZ[wv][lane] = pp;
    __builtin_amdgcn_wave_barrier();

    // ---- odd_net in fp64: lane = hidden unit h (0..63); b2o cancels ----
    double hacc = 0.0;
    #pragma unroll
    for (int f = 0; f < 32; ++f) hacc = fma(ldsZ[wv][f], (double)W1o[f * 64 + lane], hacc);
    const double bo = (double)b1o[lane];
    const double u  = tanh(hacc + bo) - tanh(bo - hacc);
    double y = u * (double)W2o[lane];
    #pragma unroll
    for (int off = 32; off; off >>= 1) y += __shfl_xor(y, off);
    if (lane == 0) out[b] = (float)y;
}

extern "C" void kernel_launch(void* const* d_in, const int* in_sizes, int n_in,
                              void* d_out, int out_size, void* d_ws, size_t ws_size,
                              hipStream_t stream) {
    const float* xs      = (const float*)d_in[0];
    const float* xs_pair = (const float*)d_in[1];
    const float* W1p     = (const float*)d_in[2];
    const float* b1p     = (const float*)d_in[3];
    const float* W2p     = (const float*)d_in[4];
    // d_in[5] = b2p (cancels in the antisymmetric difference)
    const float* W1o     = (const float*)d_in[6];
    const float* b1o     = (const float*)d_in[7];
    const float* W2o     = (const float*)d_in[8];
    // d_in[9] = b2o (cancels in odd_net(z) - odd_net(-z))
    float* out = (float*)d_out;

    hipLaunchKernelGGL(laughlin_kernel, dim3(NB / 4), dim3(256), 0, stream,
                       xs, xs_pair, W1p, b1p, W2p, W1o, b1o, W2o, out);
}

// Round 8
// 379.413 us; speedup vs baseline: 1.3614x; 1.0090x over previous
//
#include <hip/hip_runtime.h>
#include <math.h>

// LaughlinAnsatz: B=4096, N=32, D=3, Dp=4, H=64, F=32, Ho=64
// out[b] = odd_net(zs[b]) - odd_net(-zs[b])
// zs[b,f] = prod_{i<j} ( pair_net(xi,xj,xij)[f] - pair_net(xj,xi,xij)[f] )
//
//  pre_ij[k] = A_i[k] + B_j[k] + C_ij[k] + b1p[k]  (k<64; W1p row-major (10,64))
//  tanh(p1)-tanh(p2) = 2*(r2-r1), r = rcp(exp2(2*log2e*p)+1); 2x folded into W2p
//  factor_ij[f] = sum_k (r2-r1)[k] * (2*W2p[k,f])          (b2p cancels)
//  zs[f] = fp64 running product over 496 pairs (range ~e^-700, like np float64)
//  out = [tanh(zs@W1o+b1o) - tanh(-zs@W1o+b1o)]@W2o in fp64 (b2o cancels)
//
// R8: launch_bounds(256,5) to keep the 32-reg dot weights VGPR-resident
// (R7's VGPR_Count=44 proved they were demoted to per-iter L1 reloads);
// 2 waves per row (248 pairs each, parity-interleaved, perfectly balanced);
// packed-fp32 dot (v_pk_fma_f32); aI/bI hoisted behind uniform i-change branch.

#define NB 4096
#define NN 32

typedef float f32x2 __attribute__((ext_vector_type(2)));
typedef float f32x4 __attribute__((ext_vector_type(4)));

__global__ __launch_bounds__(256, 5) void laughlin_kernel(
    const float* __restrict__ xs,       // (B,32,3)
    const float* __restrict__ xs_pair,  // (B,32,32,4)
    const float* __restrict__ W1p,      // (10,64)
    const float* __restrict__ b1p,      // (64,)
    const float* __restrict__ W2p,      // (64,32)
    const float* __restrict__ W1o,      // (32,64)
    const float* __restrict__ b1o,      // (64,)
    const float* __restrict__ W2o,      // (64,1)
    float* __restrict__ out)            // (B,1)
{
    __shared__ __align__(16) float  ldsX[2][NN][4];   // xs row, float4-padded
    __shared__ __align__(16) float  ldsD[4][64];      // per-wave d/2 values
    __shared__ double ldsPP[2][2][32];                // per-row, per-wave products

    const int tid  = threadIdx.x;
    const int wv   = tid >> 6;          // 0..3
    const int lane = tid & 63;          // lane = hidden unit k in pair phase
    const int row  = wv >> 1;           // row slot in block (2 rows/block)
    const int h    = wv & 1;            // pair-parity handled by this wave
    const int hf   = lane >> 5;         // k-half in reduce phase
    const int fq   = lane & 31;         // feature f in reduce phase
    const int b    = blockIdx.x * 2 + row;

    // ---- per-lane W1p weights (lane = hidden unit k) ----
    const float wa0 = W1p[0 * 64 + lane], wa1 = W1p[1 * 64 + lane], wa2 = W1p[2 * 64 + lane];
    const float wb0 = W1p[3 * 64 + lane], wb1 = W1p[4 * 64 + lane], wb2 = W1p[5 * 64 + lane];
    const float wc0 = W1p[6 * 64 + lane], wc1 = W1p[7 * 64 + lane], wc2 = W1p[8 * 64 + lane];
    const float wc3 = W1p[9 * 64 + lane];
    const float b1  = b1p[lane];

    // ---- packed dot weights: w2pk[m] = 2*{W2p[k0,fq], W2p[k0+1,fq]} ----
    f32x2 w2pk[16];
    #pragma unroll
    for (int m = 0; m < 16; ++m) {
        const int k0 = hf * 32 + 2 * m;
        w2pk[m] = (f32x2){2.0f * W2p[k0 * 32 + fq], 2.0f * W2p[(k0 + 1) * 32 + fq]};
    }

    // ---- stage this row's xs into LDS (one wave per row) ----
    if (h == 0 && lane < NN) {
        const float* p = xs + (size_t)b * (NN * 3) + lane * 3;
        f32x4 v; v.x = p[0]; v.y = p[1]; v.z = p[2]; v.w = 0.f;
        *(f32x4*)&ldsX[row][lane][0] = v;
    }
    __syncthreads();   // uniform; ldsX read-only afterwards

    // ---- main loop: this wave handles pairs with global parity h ----
    const f32x4* xp4 = (const f32x4*)(xs_pair + (size_t)b * (NN * NN * 4));
    double pp = 1.0;
    int i = 0, j = 1;
    if (h) { if (++j == NN) { ++i; j = i + 1; } }   // skip to pair index 1
    float aI = 0.f, bI = 0.f;
    int ip = -1;
    for (int t = 0; t < 248; ++t) {
        if (i != ip) {   // uniform branch: refresh per-i terms on row change
            const f32x4 xi = *(const f32x4*)&ldsX[row][i][0];
            aI = fmaf(xi.z, wa2, fmaf(xi.y, wa1, xi.x * wa0));
            bI = fmaf(xi.z, wb2, fmaf(xi.y, wb1, xi.x * wb0));
            ip = i;
        }
        const f32x4 xj = *(const f32x4*)&ldsX[row][j][0];
        const float aJ = fmaf(xj.z, wa2, fmaf(xj.y, wa1, xj.x * wa0));
        const float bJ = fmaf(xj.z, wb2, fmaf(xj.y, wb1, xj.x * wb0));

        const f32x4 xij = xp4[(i << 5) + j];
        const float c = fmaf(xij.w, wc3, fmaf(xij.z, wc2,
                        fmaf(xij.y, wc1, fmaf(xij.x, wc0, b1))));

        const float p1 = (aI + bJ) + c;
        const float p2 = (aJ + bI) + c;
        const float e1 = __builtin_amdgcn_exp2f(p1 * 2.8853900817779268f);
        const float e2 = __builtin_amdgcn_exp2f(p2 * 2.8853900817779268f);
        const float r1 = __builtin_amdgcn_rcpf(e1 + 1.0f);
        const float r2 = __builtin_amdgcn_rcpf(e2 + 1.0f);

        ldsD[wv][lane] = r2 - r1;            // (tanh(p1)-tanh(p2))/2
        __builtin_amdgcn_wave_barrier();     // DS is in-order within a wave

        // factor[fq] = sum_{k<64} d[k]*2*W2p[k,fq]; this lane does its k-half
        const f32x4* dh = (const f32x4*)&ldsD[wv][hf << 5];
        f32x2 acc2 = (f32x2){0.f, 0.f};
        #pragma unroll
        for (int m = 0; m < 8; ++m) {
            const f32x4 dv = dh[m];
            acc2 = __builtin_elementwise_fma((f32x2){dv.x, dv.y}, w2pk[2 * m + 0], acc2);
            acc2 = __builtin_elementwise_fma((f32x2){dv.z, dv.w}, w2pk[2 * m + 1], acc2);
        }
        float acc = acc2.x + acc2.y;
        acc += __shfl_xor(acc, 32);          // full 64-sum (both halves identical)

        pp *= (double)acc;                   // fp64 running product
        __builtin_amdgcn_wave_barrier();     // reads stay before next iter's write

        if (++j == NN) { ++i; j = i + 1; }   // advance 2 pair indices
        if (++j == NN) { ++i; j = i + 1; }
    }

    // ---- combine the two waves' partial products, then odd_net ----
    if (lane < 32) ldsPP[row][h][lane] = pp;
    __syncthreads();

    if (h == 0) {
        double hacc = 0.0;                   // lane = odd_net hidden unit (64)
        #pragma unroll
        for (int f = 0; f < 32; ++f) {
            const double zf = ldsPP[row][0][f] * ldsPP[row][1][f];
            hacc = fma(zf, (double)W1o[f * 64 + lane], hacc);
        }
        const double bo = (double)b1o[lane];
        const double u  = tanh(hacc + bo) - tanh(bo - hacc);  // b2o cancels
        double y = u * (double)W2o[lane];
        #pragma unroll
        for (int off = 32; off; off >>= 1) y += __shfl_xor(y, off);
        if (lane == 0) out[b] = (float)y;
    }
}

extern "C" void kernel_launch(void* const* d_in, const int* in_sizes, int n_in,
                              void* d_out, int out_size, void* d_ws, size_t ws_size,
                              hipStream_t stream) {
    const float* xs      = (const float*)d_in[0];
    const float* xs_pair = (const float*)d_in[1];
    const float* W1p     = (const float*)d_in[2];
    const float* b1p     = (const float*)d_in[3];
    const float* W2p     = (const float*)d_in[4];
    // d_in[5] = b2p (cancels in the antisymmetric difference)
    const float* W1o     = (const float*)d_in[6];
    const float* b1o     = (const float*)d_in[7];
    const float* W2o     = (const float*)d_in[8];
    // d_in[9] = b2o (cancels in odd_net(z) - odd_net(-z))
    float* out = (float*)d_out;

    hipLaunchKernelGGL(laughlin_kernel, dim3(NB / 2), dim3(256), 0, stream,
                       xs, xs_pair, W1p, b1p, W2p, W1o, b1o, W2o, out);
}

// Round 9
// 335.619 us; speedup vs baseline: 1.5390x; 1.1305x over previous
//
#include <hip/hip_runtime.h>
#include <math.h>

// LaughlinAnsatz: B=4096, N=32, D=3, Dp=4, H=64, F=32, Ho=64
// out[b] = odd_net(zs[b]) - odd_net(-zs[b])
// zs[b,f] = prod_{i<j} ( pair_net(xi,xj,xij)[f] - pair_net(xj,xi,xij)[f] )
//
//  pre_ij[k] = A_i[k] + B_j[k] + C_ij[k] + b1p[k]   (k<64; W1p row-major (10,64))
//  tanh(p1)-tanh(p2) = 2*(e1-e2)/((e1+1)(e2+1)), e=exp2(S*p), S=2*log2(e)
//    (S folded into W1p weights/bias; the 2x folded into W2p)
//  factor_ij[f] = sum_k d[k] * (2*W2p[k,f])          (b2p cancels)
//  zs[f] = fp64 running product over 496 pairs
//  out = [tanh(zs@W1o+b1o) - tanh(-zs@W1o+b1o)]@W2o in fp64 (b2o cancels)
//
// R9: kill R8's VALU bloat. (1) asm-pin the 32 dot weights into VGPRs
// (R7/R8 VGPR_Count=44 proved the compiler re-loads them per pair);
// (2) readfirstlane h/row -> all pair bookkeeping + xij address scalarize
// (SGPR/SMEM, off the VALU pipe); (3) A/B tables in LDS: inner loop trades
// 6 FMA for one ds_read_b64 on the parallel LDS pipe; (4) merged-rcp tanh
// diff: 3 trans ops instead of 4.

#define NB 4096
#define NN 32

typedef float f32x2 __attribute__((ext_vector_type(2)));
typedef float f32x4 __attribute__((ext_vector_type(4)));

__global__ __launch_bounds__(256, 4) void laughlin_kernel(
    const float* __restrict__ xs,       // (B,32,3)
    const float* __restrict__ xs_pair,  // (B,32,32,4)
    const float* __restrict__ W1p,      // (10,64)
    const float* __restrict__ b1p,      // (64,)
    const float* __restrict__ W2p,      // (64,32)
    const float* __restrict__ W1o,      // (32,64)
    const float* __restrict__ b1o,      // (64,)
    const float* __restrict__ W2o,      // (64,1)
    float* __restrict__ out)            // (B,1)
{
    __shared__ f32x2  ldsAB[2][NN][64];  // per-row {A_n[k], B_n[k]}, S-scaled
    __shared__ __align__(16) float ldsD[4][64];
    __shared__ double ldsPP[2][2][32];

    const int tid  = threadIdx.x;
    const int wv   = tid >> 6;
    const int lane = tid & 63;           // hidden unit k in the pair phase
    const int hf   = lane >> 5;          // k-half in the dot phase
    const int row  = __builtin_amdgcn_readfirstlane(wv >> 1);  // SGPR
    const int h    = __builtin_amdgcn_readfirstlane(wv & 1);   // SGPR parity
    const int b    = blockIdx.x * 2 + row;

    // ---- per-lane W1p weights, pre-scaled by S = 2*log2(e) ----
    const float S = 2.8853900817779268f;
    const float wa0 = S * W1p[0 * 64 + lane], wa1 = S * W1p[1 * 64 + lane], wa2 = S * W1p[2 * 64 + lane];
    const float wb0 = S * W1p[3 * 64 + lane], wb1 = S * W1p[4 * 64 + lane], wb2 = S * W1p[5 * 64 + lane];
    const float wc0 = S * W1p[6 * 64 + lane], wc1 = S * W1p[7 * 64 + lane], wc2 = S * W1p[8 * 64 + lane];
    const float wc3 = S * W1p[9 * 64 + lane];
    const float b1S = S * b1p[lane];

    // ---- dot weights (x2 folded in), PINNED into VGPRs ----
    float w2c[32];
    #pragma unroll
    for (int k = 0; k < 32; ++k) w2c[k] = 2.0f * W2p[(hf * 32 + k) * 32 + (lane & 31)];
    #pragma unroll
    for (int k = 0; k < 32; ++k) asm volatile("" : "+v"(w2c[k]));

    // ---- build per-row A/B tables (S-scaled) in LDS; 2 waves split nodes ----
    for (int n = h; n < NN; n += 2) {                // n is wave-uniform
        const float* xn = xs + ((size_t)b * NN + n) * 3;
        const float x0 = xn[0], x1 = xn[1], x2 = xn[2];
        f32x2 ab;
        ab.x = fmaf(x2, wa2, fmaf(x1, wa1, x0 * wa0));   // S*A_n[lane]
        ab.y = fmaf(x2, wb2, fmaf(x1, wb1, x0 * wb0));   // S*B_n[lane]
        ldsAB[row][n][lane] = ab;
    }
    __syncthreads();    // uniform; ldsAB read-only afterwards

    // ---- main loop: this wave does pairs of parity h (248 each) ----
    const f32x4* xp4 = (const f32x4*)(xs_pair + (size_t)b * (NN * NN * 4));
    double pp = 1.0;
    int i = 0, j = 1 + h, ip = 0;        // i,j wave-uniform (SGPR)
    f32x2 abI = ldsAB[row][0][lane];
    for (int t = 0; t < 248; ++t) {
        if (i != ip) { abI = ldsAB[row][i][lane]; ip = i; }   // uniform branch
        const f32x2 abJ = ldsAB[row][j][lane];
        const f32x4 xij = xp4[(i << 5) + j];                  // uniform address
        const float c = fmaf(xij.w, wc3, fmaf(xij.z, wc2,
                        fmaf(xij.y, wc1, fmaf(xij.x, wc0, b1S))));
        const float p1 = (abI.x + c) + abJ.y;   // S*pre(i,j)
        const float p2 = (abJ.x + c) + abI.y;   // S*pre(j,i)
        const float e1 = __builtin_amdgcn_exp2f(p1);
        const float e2 = __builtin_amdgcn_exp2f(p2);
        const float den = (e1 + 1.0f) * (e2 + 1.0f);
        const float d = (e1 - e2) * __builtin_amdgcn_rcpf(den);  // (tanh1-tanh2)/2

        ldsD[wv][lane] = d;
        __builtin_amdgcn_wave_barrier();     // DS in-order within a wave

        float acc = 0.f;                     // factor[f=lane&31] (x1/2)
        const f32x4* dh = (const f32x4*)&ldsD[wv][hf << 5];
        #pragma unroll
        for (int m = 0; m < 8; ++m) {
            const f32x4 dv = dh[m];
            acc = fmaf(dv.x, w2c[4 * m + 0], acc);
            acc = fmaf(dv.y, w2c[4 * m + 1], acc);
            acc = fmaf(dv.z, w2c[4 * m + 2], acc);
            acc = fmaf(dv.w, w2c[4 * m + 3], acc);
        }
        acc += __shfl_xor(acc, 32);          // full 64-k sum
        pp *= (double)acc;                   // fp64 running product
        __builtin_amdgcn_wave_barrier();     // reads before next iter's write

        j += 2;                              // advance 2 pairs (scalar math)
        if (j >= NN) { ++i; j = i + 1 + (j - NN); }
    }

    // ---- combine the two parity-waves' products, then odd_net ----
    if (lane < 32) ldsPP[row][h][lane] = pp;
    __syncthreads();

    if (h == 0) {
        double hacc = 0.0;                   // lane = odd_net hidden unit
        #pragma unroll
        for (int f = 0; f < 32; ++f) {
            const double zf = ldsPP[row][0][f] * ldsPP[row][1][f];
            hacc = fma(zf, (double)W1o[f * 64 + lane], hacc);
        }
        const double bo = (double)b1o[lane];
        const double u  = tanh(hacc + bo) - tanh(bo - hacc);  // b2o cancels
        double y = u * (double)W2o[lane];
        #pragma unroll
        for (int off = 32; off; off >>= 1) y += __shfl_xor(y, off);
        if (lane == 0) out[b] = (float)y;
    }
}

extern "C" void kernel_launch(void* const* d_in, const int* in_sizes, int n_in,
                              void* d_out, int out_size, void* d_ws, size_t ws_size,
                              hipStream_t stream) {
    const float* xs      = (const float*)d_in[0];
    const float* xs_pair = (const float*)d_in[1];
    const float* W1p     = (const float*)d_in[2];
    const float* b1p     = (const float*)d_in[3];
    const float* W2p     = (const float*)d_in[4];
    // d_in[5] = b2p (cancels in the antisymmetric difference)
    const float* W1o     = (const float*)d_in[6];
    const float* b1o     = (const float*)d_in[7];
    const float* W2o     = (const float*)d_in[8];
    // d_in[9] = b2o (cancels in odd_net(z) - odd_net(-z))
    float* out = (float*)d_out;

    hipLaunchKernelGGL(laughlin_kernel, dim3(NB / 2), dim3(256), 0, stream,
                       xs, xs_pair, W1p, b1p, W2p, W1o, b1o, W2o, out);
}

// Round 10
// 305.149 us; speedup vs baseline: 1.6927x; 1.0999x over previous
//
#include <hip/hip_runtime.h>
#include <math.h>

// LaughlinAnsatz: B=4096, N=32, D=3, Dp=4, H=64, F=32, Ho=64
// out[b] = odd_net(zs[b]) - odd_net(-zs[b])
// zs[b,f] = prod_{i<j} ( pair_net(xi,xj,xij)[f] - pair_net(xj,xi,xij)[f] )
//
//  pre_ij[k] = A_i[k]+B_j[k]+C_ij[k]+b1p[k], k<64 (W1p row-major (10,64))
//  tanh(p1)-tanh(p2) = 2*(e1-e2)/((e1+1)(e2+1)), e=exp2(S*p), S=2*log2(e)
//  factor_ij[f] = sum_k d[k]*(2*W2p[k,f])   d=(tanh1-tanh2)/2   (b2p cancels)
//  zs[f] = fp64 running product over 496 pairs
//  out = [tanh(zs@W1o+b1o) - tanh(-zs@W1o+b1o)]@W2o in fp64 (b2o cancels)
//
// R10: the 64x32 per-pair dot moves to the MATRIX pipe. 16 pairs/batch,
// 31 batches/row, one wave per row. d and 2*W2p split hi+lo bf16 (mantissa
// truncation); factor = ah*bh + ah*bl + al*bh via mfma_f32_16x16x32_bf16
// (12 MFMAs/batch). Pair-permutations are absorbed by the product and the
// k-map cancels A<->B, so only B's n-map (lane&15, matches verified C/D
// layout) must be right. Factors multiply into per-lane fp64 products;
// cross-lane combine = 2 shfl_xor at the end.

#define NB 4096
#define NN 32

typedef float f32x4 __attribute__((ext_vector_type(4)));
typedef short bf16x8 __attribute__((ext_vector_type(8)));

__device__ __forceinline__ unsigned fbits(float x) { union { float f; unsigned u; } c; c.f = x; return c.u; }
__device__ __forceinline__ float bfloat(unsigned u) { union { float f; unsigned u; } c; c.u = u; return c.f; }

__global__ __launch_bounds__(256, 4) void laughlin_kernel(
    const float* __restrict__ xs,       // (B,32,3)
    const float* __restrict__ xs_pair,  // (B,32,32,4)
    const float* __restrict__ W1p,      // (10,64)
    const float* __restrict__ b1p,      // (64,)
    const float* __restrict__ W2p,      // (64,32)
    const float* __restrict__ W1o,      // (32,64)
    const float* __restrict__ b1o,      // (64,)
    const float* __restrict__ W2o,      // (64,1)
    float* __restrict__ out)            // (B,1)
{
    __shared__ f32x4          ldsX[4][NN];        // xs row, float4-padded
    __shared__ unsigned short ldsHi[4][16][72];   // d hi-bf16 [pair-in-batch][k], pad 72
    __shared__ unsigned short ldsLo[4][16][72];   // d lo-bf16
    __shared__ double         ldsZ[4][32];        // zs[f]

    const int tid  = threadIdx.x;
    const int wv   = tid >> 6;          // wave = row slot
    const int lane = tid & 63;          // hidden unit k in tanh phase
    const int b    = blockIdx.x * 4 + wv;

    // ---- per-lane W1p weights, pre-scaled by S = 2*log2(e) ----
    const float S = 2.8853900817779268f;
    const float wa0 = S * W1p[0 * 64 + lane], wa1 = S * W1p[1 * 64 + lane], wa2 = S * W1p[2 * 64 + lane];
    const float wb0 = S * W1p[3 * 64 + lane], wb1 = S * W1p[4 * 64 + lane], wb2 = S * W1p[5 * 64 + lane];
    const float wc0 = S * W1p[6 * 64 + lane], wc1 = S * W1p[7 * 64 + lane], wc2 = S * W1p[8 * 64 + lane];
    const float wc3 = S * W1p[9 * 64 + lane];
    const float b1S = S * b1p[lane];

    // ---- B fragments: 2*W2p split hi/lo bf16 (slot (g,e) -> k = 32s+g*8+e,
    //      n = (lane&15)+16t; k-map only needs to MATCH the A-side) ----
    const int m  = lane & 15;           // MFMA row (pair) / col (feature) index
    const int g  = lane >> 4;           // k-slot group
    bf16x8 bhi[2][2], blo[2][2];
    #pragma unroll
    for (int t = 0; t < 2; ++t)
      #pragma unroll
      for (int s = 0; s < 2; ++s) {
        bf16x8 h, l;
        #pragma unroll
        for (int e = 0; e < 8; ++e) {
          const float w = 2.0f * W2p[(32 * s + g * 8 + e) * 32 + (m + 16 * t)];
          const unsigned u = fbits(w);
          h[e] = (short)(u >> 16);
          const float lof = w - bfloat(u & 0xFFFF0000u);
          l[e] = (short)(fbits(lof) >> 16);
        }
        bhi[t][s] = h; blo[t][s] = l;
      }

    // ---- stage this row's xs ----
    if (lane < NN) {
        const float* p = xs + ((size_t)b * NN + lane) * 3;
        f32x4 v; v.x = p[0]; v.y = p[1]; v.z = p[2]; v.w = 0.f;
        ldsX[wv][lane] = v;
    }
    __builtin_amdgcn_wave_barrier();    // wave-local LDS; DS is in-order per wave

    // ---- main loop: 31 batches x 16 pairs ----
    const f32x4* xp4 = (const f32x4*)(xs_pair + (size_t)b * (NN * NN * 4));
    double pp0 = 1.0, pp1 = 1.0;        // fp64 products, features m and m+16
    int i = 0, j = 1, ip = -1;
    float aI = 0.f, bI = 0.f;

    for (int bt = 0; bt < 31; ++bt) {
        // tanh phase: lane = k, one pair at a time
        #pragma unroll 4
        for (int q = 0; q < 16; ++q) {
            if (i != ip) {              // uniform branch (i,j are scalar)
                const f32x4 xi = ldsX[wv][i];
                aI = fmaf(xi.z, wa2, fmaf(xi.y, wa1, xi.x * wa0));
                bI = fmaf(xi.z, wb2, fmaf(xi.y, wb1, xi.x * wb0));
                ip = i;
            }
            const f32x4 xj = ldsX[wv][j];
            const float aJ = fmaf(xj.z, wa2, fmaf(xj.y, wa1, xj.x * wa0));
            const float bJ = fmaf(xj.z, wb2, fmaf(xj.y, wb1, xj.x * wb0));
            const f32x4 xij = xp4[(i << 5) + j];
            const float c = fmaf(xij.w, wc3, fmaf(xij.z, wc2,
                            fmaf(xij.y, wc1, fmaf(xij.x, wc0, b1S))));
            const float p1 = (aI + c) + bJ;     // S*pre(i,j)
            const float p2 = (aJ + c) + bI;     // S*pre(j,i)
            const float e1 = __builtin_amdgcn_exp2f(p1);
            const float e2 = __builtin_amdgcn_exp2f(p2);
            const float d  = (e1 - e2) * __builtin_amdgcn_rcpf((e1 + 1.f) * (e2 + 1.f));
            const unsigned u = fbits(d);
            ldsHi[wv][q][lane] = (unsigned short)(u >> 16);          // hi = trunc bf16
            const float lof = d - bfloat(u & 0xFFFF0000u);           // exact residual
            ldsLo[wv][q][lane] = (unsigned short)(fbits(lof) >> 16); // lo = trunc bf16
            if (++j == NN) { ++i; j = i + 1; }
        }
        __builtin_amdgcn_wave_barrier();

        // A fragments: row = pair m, k-slots (g*8+e) + 32s (same map as B)
        const bf16x8 ah0 = *(const bf16x8*)&ldsHi[wv][m][g * 8];
        const bf16x8 ah1 = *(const bf16x8*)&ldsHi[wv][m][32 + g * 8];
        const bf16x8 al0 = *(const bf16x8*)&ldsLo[wv][m][g * 8];
        const bf16x8 al1 = *(const bf16x8*)&ldsLo[wv][m][32 + g * 8];
        __builtin_amdgcn_wave_barrier();    // reads stay before next batch's writes

        f32x4 acc0 = {0.f, 0.f, 0.f, 0.f};
        f32x4 acc1 = {0.f, 0.f, 0.f, 0.f};
        acc0 = __builtin_amdgcn_mfma_f32_16x16x32_bf16(al0, bhi[0][0], acc0, 0, 0, 0);
        acc0 = __builtin_amdgcn_mfma_f32_16x16x32_bf16(ah0, blo[0][0], acc0, 0, 0, 0);
        acc0 = __builtin_amdgcn_mfma_f32_16x16x32_bf16(ah0, bhi[0][0], acc0, 0, 0, 0);
        acc0 = __builtin_amdgcn_mfma_f32_16x16x32_bf16(al1, bhi[0][1], acc0, 0, 0, 0);
        acc0 = __builtin_amdgcn_mfma_f32_16x16x32_bf16(ah1, blo[0][1], acc0, 0, 0, 0);
        acc0 = __builtin_amdgcn_mfma_f32_16x16x32_bf16(ah1, bhi[0][1], acc0, 0, 0, 0);
        acc1 = __builtin_amdgcn_mfma_f32_16x16x32_bf16(al0, bhi[1][0], acc1, 0, 0, 0);
        acc1 = __builtin_amdgcn_mfma_f32_16x16x32_bf16(ah0, blo[1][0], acc1, 0, 0, 0);
        acc1 = __builtin_amdgcn_mfma_f32_16x16x32_bf16(ah0, bhi[1][0], acc1, 0, 0, 0);
        acc1 = __builtin_amdgcn_mfma_f32_16x16x32_bf16(al1, bhi[1][1], acc1, 0, 0, 0);
        acc1 = __builtin_amdgcn_mfma_f32_16x16x32_bf16(ah1, blo[1][1], acc1, 0, 0, 0);
        acc1 = __builtin_amdgcn_mfma_f32_16x16x32_bf16(ah1, bhi[1][1], acc1, 0, 0, 0);

        // 4 factors per lane per ntile (its 4 pairs) -> fp64 running product
        const float q0 = (acc0[0] * acc0[1]) * (acc0[2] * acc0[3]);
        const float q1 = (acc1[0] * acc1[1]) * (acc1[2] * acc1[3]);
        pp0 *= (double)q0;
        pp1 *= (double)q1;
    }

    // ---- combine the 4 lane-groups (disjoint pair sets) per feature ----
    pp0 *= __shfl_xor(pp0, 16);  pp0 *= __shfl_xor(pp0, 32);
    pp1 *= __shfl_xor(pp1, 16);  pp1 *= __shfl_xor(pp1, 32);
    if (lane < 16) { ldsZ[wv][lane] = pp0; ldsZ[wv][lane + 16] = pp1; }
    __builtin_amdgcn_wave_barrier();

    // ---- odd_net in fp64: lane = hidden unit h (0..63); b2o cancels ----
    double hacc = 0.0;
    #pragma unroll
    for (int f = 0; f < 32; ++f) hacc = fma(ldsZ[wv][f], (double)W1o[f * 64 + lane], hacc);
    const double bo = (double)b1o[lane];
    const double u2 = tanh(hacc + bo) - tanh(bo - hacc);
    double y = u2 * (double)W2o[lane];
    #pragma unroll
    for (int off = 32; off; off >>= 1) y += __shfl_xor(y, off);
    if (lane == 0) out[b] = (float)y;
}

extern "C" void kernel_launch(void* const* d_in, const int* in_sizes, int n_in,
                              void* d_out, int out_size, void* d_ws, size_t ws_size,
                              hipStream_t stream) {
    const float* xs      = (const float*)d_in[0];
    const float* xs_pair = (const float*)d_in[1];
    const float* W1p     = (const float*)d_in[2];
    const float* b1p     = (const float*)d_in[3];
    const float* W2p     = (const float*)d_in[4];
    // d_in[5] = b2p (cancels in the antisymmetric difference)
    const float* W1o     = (const float*)d_in[6];
    const float* b1o     = (const float*)d_in[7];
    const float* W2o     = (const float*)d_in[8];
    // d_in[9] = b2o (cancels in odd_net(z) - odd_net(-z))
    float* out = (float*)d_out;

    hipLaunchKernelGGL(laughlin_kernel, dim3(NB / 4), dim3(256), 0, stream,
                       xs, xs_pair, W1p, b1p, W2p, W1o, b1o, W2o, out);
}

// Round 11
// 250.611 us; speedup vs baseline: 2.0611x; 1.2176x over previous
//
#include <hip/hip_runtime.h>
#include <math.h>

// LaughlinAnsatz: B=4096, N=32, D=3, Dp=4, H=64, F=32, Ho=64
// out[b] = odd_net(zs[b]) - odd_net(-zs[b])
// zs[b,f] = prod_{i<j} ( pair_net(xi,xj,xij)[f] - pair_net(xj,xi,xij)[f] )
//
// R11: latency attack. (1) 2 parity waves per row (8192 waves -> ~24/CU vs 16);
// (2) next-batch xij prefetch: lane q holds pair q's float4 (addresses from a
// once-built LDS pair table, exact triangular-inverse via fp64 sqrt), broadcast
// in-loop by __shfl with literal q -> VMEM off the critical path; (3) full
// hi/lo MFMA product incl. al*bl (16 MFMAs/batch) restores accuracy margin.

#define NB 4096
#define NN 32

typedef float f32x4 __attribute__((ext_vector_type(4)));
typedef short bf16x8 __attribute__((ext_vector_type(8)));

__device__ __forceinline__ unsigned fbits(float x) { union { float f; unsigned u; } c; c.f = x; return c.u; }
__device__ __forceinline__ float bfloat(unsigned u) { union { float f; unsigned u; } c; c.u = u; return c.f; }

__global__ __launch_bounds__(256, 5) void laughlin_kernel(
    const float* __restrict__ xs,       // (B,32,3)
    const float* __restrict__ xs_pair,  // (B,32,32,4)
    const float* __restrict__ W1p,      // (10,64)
    const float* __restrict__ b1p,      // (64,)
    const float* __restrict__ W2p,      // (64,32)
    const float* __restrict__ W1o,      // (32,64)
    const float* __restrict__ b1o,      // (64,)
    const float* __restrict__ W2o,      // (64,1)
    float* __restrict__ out)            // (B,1)
{
    __shared__ f32x4          ldsX[2][NN];        // [row][node] xs, f32x4-padded
    __shared__ unsigned short ldsHi[4][16][72];   // per-wave d hi-bf16 [pair][k]
    __shared__ unsigned short ldsLo[4][16][72];   // per-wave d lo-bf16
    __shared__ unsigned short ldsTbl[2][256];     // [parity][n] -> (i<<5)|j
    __shared__ double         ldsPP[2][2][32];    // [row][parity][feature]

    const int tid  = threadIdx.x;
    const int wv   = tid >> 6;
    const int lane = tid & 63;          // hidden unit k in tanh phase
    const int row  = __builtin_amdgcn_readfirstlane(wv >> 1);
    const int h    = __builtin_amdgcn_readfirstlane(wv & 1);   // pair parity
    const int b    = blockIdx.x * 2 + row;
    const int m    = lane & 15;         // MFMA pair-row base / feature col
    const int g    = lane >> 4;         // MFMA k-slot group / row group

    // ---- per-lane W1p weights, pre-scaled by S = 2*log2(e) ----
    const float S = 2.8853900817779268f;
    const float wa0 = S * W1p[0 * 64 + lane], wa1 = S * W1p[1 * 64 + lane], wa2 = S * W1p[2 * 64 + lane];
    const float wb0 = S * W1p[3 * 64 + lane], wb1 = S * W1p[4 * 64 + lane], wb2 = S * W1p[5 * 64 + lane];
    const float wc0 = S * W1p[6 * 64 + lane], wc1 = S * W1p[7 * 64 + lane], wc2 = S * W1p[8 * 64 + lane];
    const float wc3 = S * W1p[9 * 64 + lane];
    const float b1S = S * b1p[lane];

    // ---- B fragments: 2*W2p split hi/lo bf16 (k = 32s+8g+e, n = m+16t) ----
    bf16x8 bhi[2][2], blo[2][2];
    #pragma unroll
    for (int t = 0; t < 2; ++t)
      #pragma unroll
      for (int s = 0; s < 2; ++s) {
        bf16x8 hh, ll;
        #pragma unroll
        for (int e = 0; e < 8; ++e) {
          const float w = 2.0f * W2p[(32 * s + g * 8 + e) * 32 + (m + 16 * t)];
          const unsigned u = fbits(w);
          hh[e] = (short)(u >> 16);
          ll[e] = (short)(fbits(w - bfloat(u & 0xFFFF0000u)) >> 16);
        }
        bhi[t][s] = hh; blo[t][s] = ll;
      }

    // ---- one-time staging: wv0/wv1 stage the two xs rows; wv2/wv3 build tables ----
    if (wv < 2) {
        if (lane < NN) {
            const float* p = xs + ((size_t)(blockIdx.x * 2 + wv) * NN + lane) * 3;
            f32x4 v; v.x = p[0]; v.y = p[1]; v.z = p[2]; v.w = 0.f;
            ldsX[wv][lane] = v;
        }
    } else {
        const int hh = wv - 2;          // parity of the table this wave builds
        for (int n = lane; n < 256; n += 64) {
            int p = 2 * n + hh; if (p > 494 + hh) p = 494 + hh;     // clamp tail
            const double sd = sqrt((double)(3969 - 8 * p));          // exact at boundaries
            const int i  = (int)((63.0 - sd) * 0.5);
            const int fi = 31 * i - ((i * (i - 1)) >> 1);
            const int j  = p - fi + i + 1;
            ldsTbl[hh][n] = (unsigned short)((i << 5) | j);
        }
    }
    __syncthreads();

    // ---- prefetch batch 0's xij (lane q<16 holds pair q; dups harmless) ----
    const f32x4* xp4 = (const f32x4*)(xs_pair + (size_t)b * (NN * NN * 4));
    f32x4 cur = xp4[ldsTbl[h][m]];
    f32x4 nxt;

    double pp0 = 1.0, pp1 = 1.0;        // fp64 products, features m and m+16
    int i = 0, j = 1 + h, ip = -1;      // scalar pair walker (parity h)
    float aI = 0.f, bIv = 0.f;

    auto do_pair = [&](int q) {
        if (i != ip) {                  // uniform branch: refresh per-i terms
            const f32x4 xi = ldsX[row][i];
            aI  = fmaf(xi.z, wa2, fmaf(xi.y, wa1, xi.x * wa0));
            bIv = fmaf(xi.z, wb2, fmaf(xi.y, wb1, xi.x * wb0));
            ip = i;
        }
        const f32x4 xj = ldsX[row][j];
        const float aJ = fmaf(xj.z, wa2, fmaf(xj.y, wa1, xj.x * wa0));
        const float bJ = fmaf(xj.z, wb2, fmaf(xj.y, wb1, xj.x * wb0));
        const float cx = __shfl(cur.x, q), cy = __shfl(cur.y, q);
        const float cz = __shfl(cur.z, q), cw = __shfl(cur.w, q);
        const float c = fmaf(cw, wc3, fmaf(cz, wc2, fmaf(cy, wc1, fmaf(cx, wc0, b1S))));
        const float p1 = (aI + c) + bJ;     // S*pre(i,j)
        const float p2 = (aJ + c) + bIv;    // S*pre(j,i)
        const float e1 = __builtin_amdgcn_exp2f(p1);
        const float e2 = __builtin_amdgcn_exp2f(p2);
        const float d  = (e1 - e2) * __builtin_amdgcn_rcpf((e1 + 1.f) * (e2 + 1.f));
        const unsigned u = fbits(d);
        ldsHi[wv][q][lane] = (unsigned short)(u >> 16);
        ldsLo[wv][q][lane] = (unsigned short)(fbits(d - bfloat(u & 0xFFFF0000u)) >> 16);
        j += 2;                             // advance to this wave's next pair
        if (j >= NN) { ++i; j = i + 1 + (j - NN); }
    };

    auto do_mfma = [&](bool tail) {
        __builtin_amdgcn_wave_barrier();    // DS in-order within a wave
        const bf16x8 ah0 = *(const bf16x8*)&ldsHi[wv][m][g * 8];
        const bf16x8 ah1 = *(const bf16x8*)&ldsHi[wv][m][32 + g * 8];
        const bf16x8 al0 = *(const bf16x8*)&ldsLo[wv][m][g * 8];
        const bf16x8 al1 = *(const bf16x8*)&ldsLo[wv][m][32 + g * 8];
        __builtin_amdgcn_wave_barrier();    // frag reads before next batch's writes

        f32x4 acc0 = {0.f, 0.f, 0.f, 0.f};
        f32x4 acc1 = {0.f, 0.f, 0.f, 0.f};
        acc0 = __builtin_amdgcn_mfma_f32_16x16x32_bf16(al0, blo[0][0], acc0, 0, 0, 0);
        acc0 = __builtin_amdgcn_mfma_f32_16x16x32_bf16(al0, bhi[0][0], acc0, 0, 0, 0);
        acc0 = __builtin_amdgcn_mfma_f32_16x16x32_bf16(ah0, blo[0][0], acc0, 0, 0, 0);
        acc0 = __builtin_amdgcn_mfma_f32_16x16x32_bf16(ah0, bhi[0][0], acc0, 0, 0, 0);
        acc0 = __builtin_amdgcn_mfma_f32_16x16x32_bf16(al1, blo[0][1], acc0, 0, 0, 0);
        acc0 = __builtin_amdgcn_mfma_f32_16x16x32_bf16(al1, bhi[0][1], acc0, 0, 0, 0);
        acc0 = __builtin_amdgcn_mfma_f32_16x16x32_bf16(ah1, blo[0][1], acc0, 0, 0, 0);
        acc0 = __builtin_amdgcn_mfma_f32_16x16x32_bf16(ah1, bhi[0][1], acc0, 0, 0, 0);
        acc1 = __builtin_amdgcn_mfma_f32_16x16x32_bf16(al0, blo[1][0], acc1, 0, 0, 0);
        acc1 = __builtin_amdgcn_mfma_f32_16x16x32_bf16(al0, bhi[1][0], acc1, 0, 0, 0);
        acc1 = __builtin_amdgcn_mfma_f32_16x16x32_bf16(ah0, blo[1][0], acc1, 0, 0, 0);
        acc1 = __builtin_amdgcn_mfma_f32_16x16x32_bf16(ah0, bhi[1][0], acc1, 0, 0, 0);
        acc1 = __builtin_amdgcn_mfma_f32_16x16x32_bf16(al1, blo[1][1], acc1, 0, 0, 0);
        acc1 = __builtin_amdgcn_mfma_f32_16x16x32_bf16(al1, bhi[1][1], acc1, 0, 0, 0);
        acc1 = __builtin_amdgcn_mfma_f32_16x16x32_bf16(ah1, blo[1][1], acc1, 0, 0, 0);
        acc1 = __builtin_amdgcn_mfma_f32_16x16x32_bf16(ah1, bhi[1][1], acc1, 0, 0, 0);

        float q0 = (acc0[0] * acc0[1]) * (acc0[2] * acc0[3]);   // this lane's 4 pairs
        float q1 = (acc1[0] * acc1[1]) * (acc1[2] * acc1[3]);
        if (tail && g >= 2) { q0 = 1.0f; q1 = 1.0f; }           // rows 8-15 invalid
        pp0 *= (double)q0;
        pp1 *= (double)q1;
    };

    // ---- 15 full batches + 8-pair tail (248 pairs per parity wave) ----
    for (int bt = 0; bt < 15; ++bt) {
        int n2 = 16 * (bt + 1) + m; if (n2 > 247) n2 = 247;
        nxt = xp4[ldsTbl[h][n2]];       // prefetch next batch under this batch
        #pragma unroll
        for (int q = 0; q < 16; ++q) do_pair(q);
        do_mfma(false);
        cur = nxt;
    }
    #pragma unroll
    for (int q = 0; q < 8; ++q) do_pair(q);
    do_mfma(true);

    // ---- combine lane groups (disjoint pair sets), publish per-parity products ----
    pp0 *= __shfl_xor(pp0, 16);  pp0 *= __shfl_xor(pp0, 32);
    pp1 *= __shfl_xor(pp1, 16);  pp1 *= __shfl_xor(pp1, 32);
    if (lane < 16) { ldsPP[row][h][lane] = pp0; ldsPP[row][h][lane + 16] = pp1; }
    __syncthreads();

    // ---- odd_net in fp64 (parity-0 wave of each row): lane = hidden unit ----
    if (h == 0) {
        double hacc = 0.0;
        #pragma unroll
        for (int f = 0; f < 32; ++f) {
            const double zf = ldsPP[row][0][f] * ldsPP[row][1][f];
            hacc = fma(zf, (double)W1o[f * 64 + lane], hacc);
        }
        const double bo = (double)b1o[lane];
        const double u2 = tanh(hacc + bo) - tanh(bo - hacc);    // b2o cancels
        double y = u2 * (double)W2o[lane];
        #pragma unroll
        for (int off = 32; off; off >>= 1) y += __shfl_xor(y, off);
        if (lane == 0) out[b] = (float)y;
    }
}

extern "C" void kernel_launch(void* const* d_in, const int* in_sizes, int n_in,
                              void* d_out, int out_size, void* d_ws, size_t ws_size,
                              hipStream_t stream) {
    const float* xs      = (const float*)d_in[0];
    const float* xs_pair = (const float*)d_in[1];
    const float* W1p     = (const float*)d_in[2];
    const float* b1p     = (const float*)d_in[3];
    const float* W2p     = (const float*)d_in[4];
    // d_in[5] = b2p (cancels in the antisymmetric difference)
    const float* W1o     = (const float*)d_in[6];
    const float* b1o     = (const float*)d_in[7];
    const float* W2o     = (const float*)d_in[8];
    // d_in[9] = b2o (cancels in odd_net(z) - odd_net(-z))
    float* out = (float*)d_out;

    hipLaunchKernelGGL(laughlin_kernel, dim3(NB / 2), dim3(256), 0, stream,
                       xs, xs_pair, W1p, b1p, W2p, W1o, b1o, W2o, out);
}